// Round 1
// baseline (100.567 us; speedup 1.0000x reference)
//
#include <hip/hip_runtime.h>
#include <stdint.h>

#define M_ROWS 8192
#define NCLUST 512
#define KDIM   2048

#define BM 128
#define BN 128
#define BK 64

typedef __attribute__((ext_vector_type(8))) __bf16 bf16x8;
typedef __attribute__((ext_vector_type(4))) float  f32x4;

// round-to-nearest-even f32 -> bf16 (bit pattern)
__device__ __forceinline__ unsigned short f2bf(float f) {
    unsigned u = __float_as_uint(f);
    u += 0x7FFFu + ((u >> 16) & 1u);
    return (unsigned short)(u >> 16);
}

__device__ __forceinline__ void gload_lds16(const void* g, void* l) {
    __builtin_amdgcn_global_load_lds(
        (const __attribute__((address_space(1))) void*)g,
        (__attribute__((address_space(3))) void*)l,
        16, 0, 0);
}

// ---------------------------------------------------------------------------
// Kernel 1: f32 -> bf16 convert + per-row sum of squares, rows 0..8191 = z,
// rows 8192..8703 = centroids. One wave per row. Also zeroes colsum.
// ---------------------------------------------------------------------------
__global__ __launch_bounds__(256) void k_convert(
    const float* __restrict__ z, const float* __restrict__ cent,
    unsigned short* __restrict__ zb, unsigned short* __restrict__ cb,
    float* __restrict__ zsq, float* __restrict__ csq,
    float* __restrict__ colsum)
{
    int w = threadIdx.x >> 6, lane = threadIdx.x & 63;
    int row = blockIdx.x * 4 + w;  // 0..8703

    const float* src;
    unsigned short* dst;
    float* nrm;
    int r;
    if (row < M_ROWS) { src = z + (size_t)row * KDIM; dst = zb + (size_t)row * KDIM; nrm = zsq; r = row; }
    else              { r = row - M_ROWS; src = cent + (size_t)r * KDIM; dst = cb + (size_t)r * KDIM; nrm = csq; }

    float s = 0.f;
    #pragma unroll
    for (int it = 0; it < KDIM / 256; ++it) {
        int idx = it * 256 + lane * 4;
        float4 v = *(const float4*)(src + idx);
        s += v.x * v.x + v.y * v.y + v.z * v.z + v.w * v.w;
        ushort4 o;
        o.x = f2bf(v.x); o.y = f2bf(v.y); o.z = f2bf(v.z); o.w = f2bf(v.w);
        *(ushort4*)(dst + idx) = o;
    }
    #pragma unroll
    for (int off = 32; off; off >>= 1) s += __shfl_down(s, off);
    if (lane == 0) nrm[r] = s;

    if (blockIdx.x == 0) {
        colsum[threadIdx.x] = 0.f;
        colsum[threadIdx.x + 256] = 0.f;
    }
}

// ---------------------------------------------------------------------------
// Kernel 2: bf16 MFMA GEMM (A=zb [M][K], B^T=cb [N][K]) with fused epilogue:
// Qu = 1/(1+sqrt(max(zsq+csq-2*cross,0))) written to out (Q slot, unnormalized)
// 128x128 tile, BK=64, 4 waves (2x2), double-buffered global_load_lds staging.
// ---------------------------------------------------------------------------
__global__ __launch_bounds__(256) void k_gemm_q(
    const unsigned short* __restrict__ zb, const unsigned short* __restrict__ cb,
    const float* __restrict__ zsq, const float* __restrict__ csq,
    float* __restrict__ Qu)
{
    __shared__ unsigned short As[2][BM * BK];
    __shared__ unsigned short Bs[2][BN * BK];

    const int tid  = threadIdx.x;
    const int w    = tid >> 6, lane = tid & 63;
    const int wr   = w >> 1,  wc   = w & 1;   // 2x2 wave grid, each 64x64 out
    const int bRow = blockIdx.y * BM;
    const int bCol = blockIdx.x * BN;

    f32x4 acc[4][4] = {};

    // staging geometry: per issue j (0..3): 32 rows of 128B; lane covers 16B
    const int srow = tid >> 3;          // 0..31
    const int scol = (tid & 7) * 8;     // element col 0..56
    const unsigned short* gA = zb + (size_t)(bRow + srow) * KDIM + scol;
    const unsigned short* gB = cb + (size_t)(bCol + srow) * KDIM + scol;

    auto stage = [&](int buf, int kt) {
        const int kBase = kt * BK;
        #pragma unroll
        for (int j = 0; j < 4; ++j) {
            gload_lds16(gA + (size_t)(j * 32) * KDIM + kBase, &As[buf][j * 2048 + w * 512]);
            gload_lds16(gB + (size_t)(j * 32) * KDIM + kBase, &Bs[buf][j * 2048 + w * 512]);
        }
    };

    const int arow = wr * 64 + (lane & 15);
    const int bcol = wc * 64 + (lane & 15);
    const int koff = (lane >> 4) * 8;

    auto compute = [&](int buf) {
        const unsigned short* A0 = &As[buf][0];
        const unsigned short* B0 = &Bs[buf][0];
        #pragma unroll
        for (int ks = 0; ks < 2; ++ks) {
            bf16x8 af[4], bfr[4];
            #pragma unroll
            for (int i = 0; i < 4; ++i)
                af[i] = *(const bf16x8*)&A0[(arow + i * 16) * BK + ks * 32 + koff];
            #pragma unroll
            for (int j = 0; j < 4; ++j)
                bfr[j] = *(const bf16x8*)&B0[(bcol + j * 16) * BK + ks * 32 + koff];
            #pragma unroll
            for (int i = 0; i < 4; ++i)
                #pragma unroll
                for (int j = 0; j < 4; ++j)
                    acc[i][j] = __builtin_amdgcn_mfma_f32_16x16x32_bf16(af[i], bfr[j], acc[i][j], 0, 0, 0);
        }
    };

    stage(0, 0);
    __syncthreads();
    int buf = 0;
    for (int kt = 0; kt < KDIM / BK - 1; ++kt) {
        stage(buf ^ 1, kt + 1);
        compute(buf);
        __syncthreads();   // drains vmcnt+lgkmcnt, then barrier
        buf ^= 1;
    }
    compute(buf);

    // epilogue: C/D frag mapping col=lane&15, row=(lane>>4)*4+reg (m89-verified)
    const int col0 = bCol + wc * 64 + (lane & 15);
    const int row0 = bRow + wr * 64 + (lane >> 4) * 4;
    #pragma unroll
    for (int j = 0; j < 4; ++j) {
        const int col = col0 + j * 16;
        const float cs = csq[col];
        #pragma unroll
        for (int i = 0; i < 4; ++i) {
            const int rowb = row0 + i * 16;
            #pragma unroll
            for (int r = 0; r < 4; ++r) {
                const int row = rowb + r;
                const float cross = acc[i][j][r];
                float d2 = zsq[row] + cs - 2.0f * cross;
                d2 = fmaxf(d2, 0.0f);
                const float sim = sqrtf(d2);
                Qu[(size_t)row * NCLUST + col] = 1.0f / (1.0f + sim);
            }
        }
    }
}

// ---------------------------------------------------------------------------
// Kernel 3: row-normalize Q in place + column sums (LDS reduce -> atomics).
// One wave per row; block handles 64 rows.
// ---------------------------------------------------------------------------
__global__ __launch_bounds__(256) void k_rownorm_colsum(
    float* __restrict__ Q, float* __restrict__ colsum)
{
    __shared__ float part[4][NCLUST];
    const int tid = threadIdx.x, w = tid >> 6, lane = tid & 63;
    float ca[8] = {0, 0, 0, 0, 0, 0, 0, 0};
    const int rbase = blockIdx.x * 64;

    for (int rr = 0; rr < 16; ++rr) {
        const int row = rbase + w + rr * 4;
        float* rp = Q + (size_t)row * NCLUST;
        float4 v0 = *(float4*)(rp + lane * 4);
        float4 v1 = *(float4*)(rp + 256 + lane * 4);
        float s = v0.x + v0.y + v0.z + v0.w + v1.x + v1.y + v1.z + v1.w;
        #pragma unroll
        for (int off = 32; off; off >>= 1) s += __shfl_down(s, off);
        s = __shfl(s, 0);
        const float inv = 1.0f / s;
        v0.x *= inv; v0.y *= inv; v0.z *= inv; v0.w *= inv;
        v1.x *= inv; v1.y *= inv; v1.z *= inv; v1.w *= inv;
        *(float4*)(rp + lane * 4) = v0;
        *(float4*)(rp + 256 + lane * 4) = v1;
        ca[0] += v0.x; ca[1] += v0.y; ca[2] += v0.z; ca[3] += v0.w;
        ca[4] += v1.x; ca[5] += v1.y; ca[6] += v1.z; ca[7] += v1.w;
    }
    #pragma unroll
    for (int c = 0; c < 4; ++c) {
        part[w][lane * 4 + c]       = ca[c];
        part[w][256 + lane * 4 + c] = ca[4 + c];
    }
    __syncthreads();
    const float t0 = part[0][tid] + part[1][tid] + part[2][tid] + part[3][tid];
    const float t1 = part[0][tid + 256] + part[1][tid + 256] + part[2][tid + 256] + part[3][tid + 256];
    atomicAdd(&colsum[tid], t0);
    atomicAdd(&colsum[tid + 256], t1);
}

// ---------------------------------------------------------------------------
// Kernel 4: P = rownorm(Q^2 / colsum). One wave per row.
// ---------------------------------------------------------------------------
__global__ __launch_bounds__(256) void k_p(
    const float* __restrict__ Q, const float* __restrict__ colsum,
    float* __restrict__ P)
{
    const int w = threadIdx.x >> 6, lane = threadIdx.x & 63;
    const int row = blockIdx.x * 4 + w;
    const float* qp = Q + (size_t)row * NCLUST;
    float4 q0 = *(const float4*)(qp + lane * 4);
    float4 q1 = *(const float4*)(qp + 256 + lane * 4);
    float4 c0 = *(const float4*)(colsum + lane * 4);
    float4 c1 = *(const float4*)(colsum + 256 + lane * 4);
    float4 p0, p1;
    p0.x = q0.x * q0.x / c0.x; p0.y = q0.y * q0.y / c0.y;
    p0.z = q0.z * q0.z / c0.z; p0.w = q0.w * q0.w / c0.w;
    p1.x = q1.x * q1.x / c1.x; p1.y = q1.y * q1.y / c1.y;
    p1.z = q1.z * q1.z / c1.z; p1.w = q1.w * q1.w / c1.w;
    float s = p0.x + p0.y + p0.z + p0.w + p1.x + p1.y + p1.z + p1.w;
    #pragma unroll
    for (int off = 32; off; off >>= 1) s += __shfl_down(s, off);
    s = __shfl(s, 0);
    const float inv = 1.0f / s;
    p0.x *= inv; p0.y *= inv; p0.z *= inv; p0.w *= inv;
    p1.x *= inv; p1.y *= inv; p1.z *= inv; p1.w *= inv;
    float* op = P + (size_t)row * NCLUST;
    *(float4*)(op + lane * 4) = p0;
    *(float4*)(op + 256 + lane * 4) = p1;
}

extern "C" void kernel_launch(void* const* d_in, const int* in_sizes, int n_in,
                              void* d_out, int out_size, void* d_ws, size_t ws_size,
                              hipStream_t stream) {
    const float* z    = (const float*)d_in[0];
    const float* cent = (const float*)d_in[1];
    float* out = (float*)d_out;

    // workspace layout
    char* ws = (char*)d_ws;
    unsigned short* zb = (unsigned short*)ws;                         // 32 MiB
    unsigned short* cb = (unsigned short*)(ws + 33554432);            // 2 MiB
    float* zsq    = (float*)(ws + 33554432 + 2097152);                // 32 KiB
    float* csq    = (float*)(ws + 33554432 + 2097152 + 32768);        // 2 KiB
    float* colsum = (float*)(ws + 33554432 + 2097152 + 32768 + 2048); // 2 KiB

    float* Q = out;                                  // (8192, 512)
    float* P = out + (size_t)M_ROWS * NCLUST;        // (8192, 512)

    k_convert<<<dim3((M_ROWS + NCLUST) / 4), dim3(256), 0, stream>>>(
        z, cent, zb, cb, zsq, csq, colsum);

    k_gemm_q<<<dim3(NCLUST / BN, M_ROWS / BM), dim3(256), 0, stream>>>(
        zb, cb, zsq, csq, Q);

    k_rownorm_colsum<<<dim3(M_ROWS / 64), dim3(256), 0, stream>>>(Q, colsum);

    k_p<<<dim3(M_ROWS / 4), dim3(256), 0, stream>>>(Q, colsum, P);
}

// Round 2
// 98.386 us; speedup vs baseline: 1.0222x; 1.0222x over previous
//
#include <hip/hip_runtime.h>
#include <stdint.h>

#define M_ROWS 8192
#define NCLUST 512
#define KDIM   2048

#define BM 128
#define BN 64
#define BK 64

typedef __attribute__((ext_vector_type(8))) __bf16 bf16x8;
typedef __attribute__((ext_vector_type(4))) float  f32x4;

// round-to-nearest-even f32 -> bf16 (bit pattern)
__device__ __forceinline__ unsigned short f2bf(float f) {
    unsigned u = __float_as_uint(f);
    u += 0x7FFFu + ((u >> 16) & 1u);
    return (unsigned short)(u >> 16);
}

__device__ __forceinline__ void gload_lds16(const void* g, void* l) {
    __builtin_amdgcn_global_load_lds(
        (const __attribute__((address_space(1))) void*)g,
        (__attribute__((address_space(3))) void*)l,
        16, 0, 0);
}

// ---------------------------------------------------------------------------
// Kernel 1: f32 -> bf16 convert + per-row sum of squares, rows 0..8191 = z,
// rows 8192..8703 = centroids. One wave per row. Also zeroes colsum.
// ---------------------------------------------------------------------------
__global__ __launch_bounds__(256) void k_convert(
    const float* __restrict__ z, const float* __restrict__ cent,
    unsigned short* __restrict__ zb, unsigned short* __restrict__ cb,
    float* __restrict__ zsq, float* __restrict__ csq,
    float* __restrict__ colsum)
{
    int w = threadIdx.x >> 6, lane = threadIdx.x & 63;
    int row = blockIdx.x * 4 + w;  // 0..8703

    const float* src;
    unsigned short* dst;
    float* nrm;
    int r;
    if (row < M_ROWS) { src = z + (size_t)row * KDIM; dst = zb + (size_t)row * KDIM; nrm = zsq; r = row; }
    else              { r = row - M_ROWS; src = cent + (size_t)r * KDIM; dst = cb + (size_t)r * KDIM; nrm = csq; }

    float s = 0.f;
    #pragma unroll
    for (int it = 0; it < KDIM / 256; ++it) {
        int idx = it * 256 + lane * 4;
        float4 v = *(const float4*)(src + idx);
        s += v.x * v.x + v.y * v.y + v.z * v.z + v.w * v.w;
        ushort4 o;
        o.x = f2bf(v.x); o.y = f2bf(v.y); o.z = f2bf(v.z); o.w = f2bf(v.w);
        *(ushort4*)(dst + idx) = o;
    }
    #pragma unroll
    for (int off = 32; off; off >>= 1) s += __shfl_down(s, off);
    if (lane == 0) nrm[r] = s;

    if (blockIdx.x == 0) {
        colsum[threadIdx.x] = 0.f;
        colsum[threadIdx.x + 256] = 0.f;
    }
}

// ---------------------------------------------------------------------------
// Kernel 2: bf16 MFMA GEMM (A=zb [M][K], B^T=cb [N][K]) with fused epilogue:
// Qu = 1/(1+sqrt(max(zsq+csq-2*cross,0))) written to out (Q slot, unnormalized)
// 128x64 tile, BK=64, 4 waves (2x2, each 64x32 out), double-buffered
// global_load_lds staging. Grid 8x64 = 512 blocks -> 2 blocks/CU resident
// (LDS 48 KiB) so the second block's waves cover the barrier drain.
// ---------------------------------------------------------------------------
__global__ __launch_bounds__(256) void k_gemm_q(
    const unsigned short* __restrict__ zb, const unsigned short* __restrict__ cb,
    const float* __restrict__ zsq, const float* __restrict__ csq,
    float* __restrict__ Qu)
{
    __shared__ unsigned short As[2][BM * BK];   // 16 KiB x2
    __shared__ unsigned short Bs[2][BN * BK];   //  8 KiB x2

    const int tid  = threadIdx.x;
    const int w    = tid >> 6, lane = tid & 63;
    const int wr   = w >> 1,  wc   = w & 1;   // 2x2 wave grid, each 64x32 out
    const int bRow = blockIdx.y * BM;
    const int bCol = blockIdx.x * BN;

    f32x4 acc[4][2] = {};

    // staging geometry: per issue j: 32 rows of 128B; each lane covers 16B
    const int srow = tid >> 3;          // 0..31
    const int scol = (tid & 7) * 8;     // element col 0..56
    const unsigned short* gA = zb + (size_t)(bRow + srow) * KDIM + scol;
    const unsigned short* gB = cb + (size_t)(bCol + srow) * KDIM + scol;

    auto stage = [&](int buf, int kt) {
        const int kBase = kt * BK;
        #pragma unroll
        for (int j = 0; j < 4; ++j)
            gload_lds16(gA + (size_t)(j * 32) * KDIM + kBase, &As[buf][j * 2048 + w * 512]);
        #pragma unroll
        for (int j = 0; j < 2; ++j)
            gload_lds16(gB + (size_t)(j * 32) * KDIM + kBase, &Bs[buf][j * 2048 + w * 512]);
    };

    const int arow = wr * 64 + (lane & 15);
    const int bcol = wc * 32 + (lane & 15);
    const int koff = (lane >> 4) * 8;

    auto compute = [&](int buf) {
        const unsigned short* A0 = &As[buf][0];
        const unsigned short* B0 = &Bs[buf][0];
        #pragma unroll
        for (int ks = 0; ks < 2; ++ks) {
            bf16x8 af[4], bfr[2];
            #pragma unroll
            for (int i = 0; i < 4; ++i)
                af[i] = *(const bf16x8*)&A0[(arow + i * 16) * BK + ks * 32 + koff];
            #pragma unroll
            for (int j = 0; j < 2; ++j)
                bfr[j] = *(const bf16x8*)&B0[(bcol + j * 16) * BK + ks * 32 + koff];
            #pragma unroll
            for (int i = 0; i < 4; ++i)
                #pragma unroll
                for (int j = 0; j < 2; ++j)
                    acc[i][j] = __builtin_amdgcn_mfma_f32_16x16x32_bf16(af[i], bfr[j], acc[i][j], 0, 0, 0);
        }
    };

    stage(0, 0);
    __syncthreads();
    int buf = 0;
    for (int kt = 0; kt < KDIM / BK - 1; ++kt) {
        stage(buf ^ 1, kt + 1);
        compute(buf);
        __syncthreads();   // drains vmcnt+lgkmcnt, then barrier
        buf ^= 1;
    }
    compute(buf);

    // epilogue: C/D frag mapping col=lane&15, row=(lane>>4)*4+reg (m89-verified)
    const int col0 = bCol + wc * 32 + (lane & 15);
    const int row0 = bRow + wr * 64 + (lane >> 4) * 4;
    #pragma unroll
    for (int j = 0; j < 2; ++j) {
        const int col = col0 + j * 16;
        const float cs = csq[col];
        #pragma unroll
        for (int i = 0; i < 4; ++i) {
            const int rowb = row0 + i * 16;
            #pragma unroll
            for (int r = 0; r < 4; ++r) {
                const int row = rowb + r;
                const float cross = acc[i][j][r];
                float d2 = zsq[row] + cs - 2.0f * cross;
                d2 = fmaxf(d2, 0.0f);
                const float sim = sqrtf(d2);
                Qu[(size_t)row * NCLUST + col] = 1.0f / (1.0f + sim);
            }
        }
    }
}

// ---------------------------------------------------------------------------
// Kernel 3: row-normalize Q in place + column sums (LDS reduce -> atomics).
// One wave per row; block handles 64 rows.
// ---------------------------------------------------------------------------
__global__ __launch_bounds__(256) void k_rownorm_colsum(
    float* __restrict__ Q, float* __restrict__ colsum)
{
    __shared__ float part[4][NCLUST];
    const int tid = threadIdx.x, w = tid >> 6, lane = tid & 63;
    float ca[8] = {0, 0, 0, 0, 0, 0, 0, 0};
    const int rbase = blockIdx.x * 64;

    for (int rr = 0; rr < 16; ++rr) {
        const int row = rbase + w + rr * 4;
        float* rp = Q + (size_t)row * NCLUST;
        float4 v0 = *(float4*)(rp + lane * 4);
        float4 v1 = *(float4*)(rp + 256 + lane * 4);
        float s = v0.x + v0.y + v0.z + v0.w + v1.x + v1.y + v1.z + v1.w;
        #pragma unroll
        for (int off = 32; off; off >>= 1) s += __shfl_down(s, off);
        s = __shfl(s, 0);
        const float inv = 1.0f / s;
        v0.x *= inv; v0.y *= inv; v0.z *= inv; v0.w *= inv;
        v1.x *= inv; v1.y *= inv; v1.z *= inv; v1.w *= inv;
        *(float4*)(rp + lane * 4) = v0;
        *(float4*)(rp + 256 + lane * 4) = v1;
        ca[0] += v0.x; ca[1] += v0.y; ca[2] += v0.z; ca[3] += v0.w;
        ca[4] += v1.x; ca[5] += v1.y; ca[6] += v1.z; ca[7] += v1.w;
    }
    #pragma unroll
    for (int c = 0; c < 4; ++c) {
        part[w][lane * 4 + c]       = ca[c];
        part[w][256 + lane * 4 + c] = ca[4 + c];
    }
    __syncthreads();
    const float t0 = part[0][tid] + part[1][tid] + part[2][tid] + part[3][tid];
    const float t1 = part[0][tid + 256] + part[1][tid + 256] + part[2][tid + 256] + part[3][tid + 256];
    atomicAdd(&colsum[tid], t0);
    atomicAdd(&colsum[tid + 256], t1);
}

// ---------------------------------------------------------------------------
// Kernel 4: P = rownorm(Q^2 / colsum). One wave per row.
// ---------------------------------------------------------------------------
__global__ __launch_bounds__(256) void k_p(
    const float* __restrict__ Q, const float* __restrict__ colsum,
    float* __restrict__ P)
{
    const int w = threadIdx.x >> 6, lane = threadIdx.x & 63;
    const int row = blockIdx.x * 4 + w;
    const float* qp = Q + (size_t)row * NCLUST;
    float4 q0 = *(const float4*)(qp + lane * 4);
    float4 q1 = *(const float4*)(qp + 256 + lane * 4);
    float4 c0 = *(const float4*)(colsum + lane * 4);
    float4 c1 = *(const float4*)(colsum + 256 + lane * 4);
    float4 p0, p1;
    p0.x = q0.x * q0.x / c0.x; p0.y = q0.y * q0.y / c0.y;
    p0.z = q0.z * q0.z / c0.z; p0.w = q0.w * q0.w / c0.w;
    p1.x = q1.x * q1.x / c1.x; p1.y = q1.y * q1.y / c1.y;
    p1.z = q1.z * q1.z / c1.z; p1.w = q1.w * q1.w / c1.w;
    float s = p0.x + p0.y + p0.z + p0.w + p1.x + p1.y + p1.z + p1.w;
    #pragma unroll
    for (int off = 32; off; off >>= 1) s += __shfl_down(s, off);
    s = __shfl(s, 0);
    const float inv = 1.0f / s;
    p0.x *= inv; p0.y *= inv; p0.z *= inv; p0.w *= inv;
    p1.x *= inv; p1.y *= inv; p1.z *= inv; p1.w *= inv;
    float* op = P + (size_t)row * NCLUST;
    *(float4*)(op + lane * 4) = p0;
    *(float4*)(op + 256 + lane * 4) = p1;
}

extern "C" void kernel_launch(void* const* d_in, const int* in_sizes, int n_in,
                              void* d_out, int out_size, void* d_ws, size_t ws_size,
                              hipStream_t stream) {
    const float* z    = (const float*)d_in[0];
    const float* cent = (const float*)d_in[1];
    float* out = (float*)d_out;

    // workspace layout
    char* ws = (char*)d_ws;
    unsigned short* zb = (unsigned short*)ws;                         // 32 MiB
    unsigned short* cb = (unsigned short*)(ws + 33554432);            // 2 MiB
    float* zsq    = (float*)(ws + 33554432 + 2097152);                // 32 KiB
    float* csq    = (float*)(ws + 33554432 + 2097152 + 32768);        // 2 KiB
    float* colsum = (float*)(ws + 33554432 + 2097152 + 32768 + 2048); // 2 KiB

    float* Q = out;                                  // (8192, 512)
    float* P = out + (size_t)M_ROWS * NCLUST;        // (8192, 512)

    k_convert<<<dim3((M_ROWS + NCLUST) / 4), dim3(256), 0, stream>>>(
        z, cent, zb, cb, zsq, csq, colsum);

    k_gemm_q<<<dim3(NCLUST / BN, M_ROWS / BM), dim3(256), 0, stream>>>(
        zb, cb, zsq, csq, Q);

    k_rownorm_colsum<<<dim3(M_ROWS / 64), dim3(256), 0, stream>>>(Q, colsum);

    k_p<<<dim3(M_ROWS / 4), dim3(256), 0, stream>>>(Q, colsum, P);
}

// Round 3
// 86.350 us; speedup vs baseline: 1.1646x; 1.1394x over previous
//
#include <hip/hip_runtime.h>
#include <stdint.h>

#define M_ROWS 8192
#define NCLUST 512
#define KDIM   2048

#define BM 128
#define BN 128
#define BK 32

typedef __attribute__((ext_vector_type(8))) __bf16 bf16x8;
typedef __attribute__((ext_vector_type(4))) float  f32x4;

// round-to-nearest-even f32 -> bf16 (bit pattern)
__device__ __forceinline__ unsigned short f2bf(float f) {
    unsigned u = __float_as_uint(f);
    u += 0x7FFFu + ((u >> 16) & 1u);
    return (unsigned short)(u >> 16);
}

__device__ __forceinline__ void gload_lds16(const void* g, void* l) {
    __builtin_amdgcn_global_load_lds(
        (const __attribute__((address_space(1))) void*)g,
        (__attribute__((address_space(3))) void*)l,
        16, 0, 0);
}

// ---------------------------------------------------------------------------
// Kernel 1: f32 -> bf16 convert + per-row sum of squares. Also zeroes colsum.
// ---------------------------------------------------------------------------
__global__ __launch_bounds__(256) void k_convert(
    const float* __restrict__ z, const float* __restrict__ cent,
    unsigned short* __restrict__ zb, unsigned short* __restrict__ cb,
    float* __restrict__ zsq, float* __restrict__ csq,
    float* __restrict__ colsum)
{
    int w = threadIdx.x >> 6, lane = threadIdx.x & 63;
    int row = blockIdx.x * 4 + w;  // 0..8703

    const float* src;
    unsigned short* dst;
    float* nrm;
    int r;
    if (row < M_ROWS) { src = z + (size_t)row * KDIM; dst = zb + (size_t)row * KDIM; nrm = zsq; r = row; }
    else              { r = row - M_ROWS; src = cent + (size_t)r * KDIM; dst = cb + (size_t)r * KDIM; nrm = csq; }

    float s = 0.f;
    #pragma unroll
    for (int it = 0; it < KDIM / 256; ++it) {
        int idx = it * 256 + lane * 4;
        float4 v = *(const float4*)(src + idx);
        s += v.x * v.x + v.y * v.y + v.z * v.z + v.w * v.w;
        ushort4 o;
        o.x = f2bf(v.x); o.y = f2bf(v.y); o.z = f2bf(v.z); o.w = f2bf(v.w);
        *(ushort4*)(dst + idx) = o;
    }
    #pragma unroll
    for (int off = 32; off; off >>= 1) s += __shfl_down(s, off);
    if (lane == 0) nrm[r] = s;

    if (blockIdx.x == 0) {
        colsum[threadIdx.x] = 0.f;
        colsum[threadIdx.x + 256] = 0.f;
    }
}

// ---------------------------------------------------------------------------
// Kernel 2: split-K bf16 MFMA partial GEMM. 128x128 tile, BK=32, 4 waves
// (2x2, each 64x64 = acc[4][4]).  blockIdx.z = K-chunk; partial cross written
// to one of p0..p3 (f32).  LDS 32 KiB -> 4 blocks/CU co-resident at grid
// 4x64x4 = 1024, pipelining the per-K-step barrier drains.
// LDS bank swizzle: row = 4 slots of 16B; stored slot t holds global slot
// t ^ ((row>>1)&3)  (pre-swizzled global source, swizzled ds_read; linear
// LDS dest as global_load_lds requires).  Spreads the 16-lane column read
// across all 8 bank-quads (2-way = free).
// ---------------------------------------------------------------------------
__global__ __launch_bounds__(256) void k_gemm_part(
    const unsigned short* __restrict__ zb, const unsigned short* __restrict__ cb,
    float* __restrict__ p0, float* __restrict__ p1,
    float* __restrict__ p2, float* __restrict__ p3,
    int nkt)
{
    __shared__ unsigned short As[2][BM * BK];   // 8 KiB x2
    __shared__ unsigned short Bs[2][BN * BK];   // 8 KiB x2

    const int tid  = threadIdx.x;
    const int w    = tid >> 6, lane = tid & 63;
    const int wr   = w >> 1,  wc   = w & 1;
    const int bRow = blockIdx.y * BM;
    const int bCol = blockIdx.x * BN;
    const int kb0  = blockIdx.z * nkt * BK;

    f32x4 acc[4][4] = {};

    // staging: 16 rows per 1KB wave issue; linear LDS dest (base + lane*16).
    // global source column slot pre-swizzled: (lane&3) ^ ((lane>>3)&3)
    const int srow = lane >> 2;
    const int scol = ((lane & 3) ^ ((lane >> 3) & 3)) * 8;
    const unsigned short* gA = zb + (size_t)bRow * KDIM + kb0 + scol;
    const unsigned short* gB = cb + (size_t)bCol * KDIM + kb0 + scol;

    auto stage = [&](int buf, int kt) {
        const int kb = kt * BK;
        #pragma unroll
        for (int jj = 0; jj < 2; ++jj) {
            const int rg = w * 2 + jj;   // 16-row group 0..7
            gload_lds16(gA + (size_t)(rg * 16 + srow) * KDIM + kb, &As[buf][rg * 512]);
            gload_lds16(gB + (size_t)(rg * 16 + srow) * KDIM + kb, &Bs[buf][rg * 512]);
        }
    };

    const int arowb = wr * 64 + (lane & 15);
    const int bcolb = wc * 64 + (lane & 15);
    const int s     = lane >> 4;

    auto compute = [&](int buf) {
        const unsigned short* A0 = &As[buf][0];
        const unsigned short* B0 = &Bs[buf][0];
        bf16x8 af[4], bfr[4];
        #pragma unroll
        for (int i = 0; i < 4; ++i) {
            const int row = arowb + i * 16;
            const int sp  = s ^ ((row >> 1) & 3);
            af[i] = *(const bf16x8*)&A0[row * BK + sp * 8];
        }
        #pragma unroll
        for (int j = 0; j < 4; ++j) {
            const int row = bcolb + j * 16;
            const int sp  = s ^ ((row >> 1) & 3);
            bfr[j] = *(const bf16x8*)&B0[row * BK + sp * 8];
        }
        #pragma unroll
        for (int i = 0; i < 4; ++i)
            #pragma unroll
            for (int j = 0; j < 4; ++j)
                acc[i][j] = __builtin_amdgcn_mfma_f32_16x16x32_bf16(af[i], bfr[j], acc[i][j], 0, 0, 0);
    };

    stage(0, 0);
    __syncthreads();
    int buf = 0;
    for (int kt = 0; kt < nkt - 1; ++kt) {
        stage(buf ^ 1, kt + 1);
        compute(buf);
        __syncthreads();
        buf ^= 1;
    }
    compute(buf);

    float* dst = (blockIdx.z == 0) ? p0 : (blockIdx.z == 1) ? p1 :
                 (blockIdx.z == 2) ? p2 : p3;
    // C/D frag mapping: col=lane&15, row=(lane>>4)*4+reg (m89-verified)
    const int col0 = bCol + wc * 64 + (lane & 15);
    const int row0 = bRow + wr * 64 + (lane >> 4) * 4;
    #pragma unroll
    for (int j = 0; j < 4; ++j) {
        const int col = col0 + j * 16;
        #pragma unroll
        for (int i = 0; i < 4; ++i)
            #pragma unroll
            for (int r = 0; r < 4; ++r)
                dst[(size_t)(row0 + i * 16 + r) * NCLUST + col] = acc[i][j][r];
    }
}

// ---------------------------------------------------------------------------
// Kernel 3: combine partials -> Q = 1/(1+sqrt(max(zsq+csq-2*cross,0))),
// row-normalize, column-sum (LDS reduce -> atomics).  32 rows/block.
// NOTE: Q aliases p0 (and for NPART==2, p1 aliases the P slot) -- reads of a
// row complete before that row's Q write; no __restrict__ on aliased ptrs.
// ---------------------------------------------------------------------------
template<int NPART>
__global__ __launch_bounds__(256) void k_q_norm(
    const float* p0, const float* p1,
    const float* __restrict__ p2, const float* __restrict__ p3,
    const float* __restrict__ zsq, const float* __restrict__ csq,
    float* Q, float* __restrict__ colsum)
{
    __shared__ float part[4][NCLUST];
    const int tid = threadIdx.x, w = tid >> 6, lane = tid & 63;
    float ca[8] = {0, 0, 0, 0, 0, 0, 0, 0};
    const int rbase = blockIdx.x * 32;

    const float4 cs0 = *(const float4*)(csq + lane * 4);
    const float4 cs1 = *(const float4*)(csq + 256 + lane * 4);

    for (int rr = 0; rr < 8; ++rr) {
        const int row = rbase + w + rr * 4;
        const size_t off = (size_t)row * NCLUST;
        float4 x0 = *(const float4*)(p0 + off + lane * 4);
        float4 x1 = *(const float4*)(p0 + off + 256 + lane * 4);
        {
            float4 y0 = *(const float4*)(p1 + off + lane * 4);
            float4 y1 = *(const float4*)(p1 + off + 256 + lane * 4);
            x0.x += y0.x; x0.y += y0.y; x0.z += y0.z; x0.w += y0.w;
            x1.x += y1.x; x1.y += y1.y; x1.z += y1.z; x1.w += y1.w;
        }
        if (NPART == 4) {
            float4 y0 = *(const float4*)(p2 + off + lane * 4);
            float4 y1 = *(const float4*)(p2 + off + 256 + lane * 4);
            float4 u0 = *(const float4*)(p3 + off + lane * 4);
            float4 u1 = *(const float4*)(p3 + off + 256 + lane * 4);
            x0.x += y0.x + u0.x; x0.y += y0.y + u0.y;
            x0.z += y0.z + u0.z; x0.w += y0.w + u0.w;
            x1.x += y1.x + u1.x; x1.y += y1.y + u1.y;
            x1.z += y1.z + u1.z; x1.w += y1.w + u1.w;
        }
        const float zr = zsq[row];
        float4 q0, q1;
        q0.x = 1.0f / (1.0f + sqrtf(fmaxf(zr + cs0.x - 2.0f * x0.x, 0.0f)));
        q0.y = 1.0f / (1.0f + sqrtf(fmaxf(zr + cs0.y - 2.0f * x0.y, 0.0f)));
        q0.z = 1.0f / (1.0f + sqrtf(fmaxf(zr + cs0.z - 2.0f * x0.z, 0.0f)));
        q0.w = 1.0f / (1.0f + sqrtf(fmaxf(zr + cs0.w - 2.0f * x0.w, 0.0f)));
        q1.x = 1.0f / (1.0f + sqrtf(fmaxf(zr + cs1.x - 2.0f * x1.x, 0.0f)));
        q1.y = 1.0f / (1.0f + sqrtf(fmaxf(zr + cs1.y - 2.0f * x1.y, 0.0f)));
        q1.z = 1.0f / (1.0f + sqrtf(fmaxf(zr + cs1.z - 2.0f * x1.z, 0.0f)));
        q1.w = 1.0f / (1.0f + sqrtf(fmaxf(zr + cs1.w - 2.0f * x1.w, 0.0f)));

        float sum = q0.x + q0.y + q0.z + q0.w + q1.x + q1.y + q1.z + q1.w;
        #pragma unroll
        for (int off2 = 32; off2; off2 >>= 1) sum += __shfl_down(sum, off2);
        sum = __shfl(sum, 0);
        const float inv = 1.0f / sum;
        q0.x *= inv; q0.y *= inv; q0.z *= inv; q0.w *= inv;
        q1.x *= inv; q1.y *= inv; q1.z *= inv; q1.w *= inv;
        *(float4*)(Q + off + lane * 4) = q0;
        *(float4*)(Q + off + 256 + lane * 4) = q1;
        ca[0] += q0.x; ca[1] += q0.y; ca[2] += q0.z; ca[3] += q0.w;
        ca[4] += q1.x; ca[5] += q1.y; ca[6] += q1.z; ca[7] += q1.w;
    }
    #pragma unroll
    for (int c = 0; c < 4; ++c) {
        part[w][lane * 4 + c]       = ca[c];
        part[w][256 + lane * 4 + c] = ca[4 + c];
    }
    __syncthreads();
    const float t0 = part[0][tid] + part[1][tid] + part[2][tid] + part[3][tid];
    const float t1 = part[0][tid + 256] + part[1][tid + 256] + part[2][tid + 256] + part[3][tid + 256];
    atomicAdd(&colsum[tid], t0);
    atomicAdd(&colsum[tid + 256], t1);
}

// ---------------------------------------------------------------------------
// Kernel 4: P = rownorm(Q^2 / colsum). One wave per row.
// ---------------------------------------------------------------------------
__global__ __launch_bounds__(256) void k_p(
    const float* __restrict__ Q, const float* __restrict__ colsum,
    float* __restrict__ P)
{
    const int w = threadIdx.x >> 6, lane = threadIdx.x & 63;
    const int row = blockIdx.x * 4 + w;
    const float* qp = Q + (size_t)row * NCLUST;
    float4 q0 = *(const float4*)(qp + lane * 4);
    float4 q1 = *(const float4*)(qp + 256 + lane * 4);
    float4 c0 = *(const float4*)(colsum + lane * 4);
    float4 c1 = *(const float4*)(colsum + 256 + lane * 4);
    float4 p0, p1;
    p0.x = q0.x * q0.x / c0.x; p0.y = q0.y * q0.y / c0.y;
    p0.z = q0.z * q0.z / c0.z; p0.w = q0.w * q0.w / c0.w;
    p1.x = q1.x * q1.x / c1.x; p1.y = q1.y * q1.y / c1.y;
    p1.z = q1.z * q1.z / c1.z; p1.w = q1.w * q1.w / c1.w;
    float s = p0.x + p0.y + p0.z + p0.w + p1.x + p1.y + p1.z + p1.w;
    #pragma unroll
    for (int off = 32; off; off >>= 1) s += __shfl_down(s, off);
    s = __shfl(s, 0);
    const float inv = 1.0f / s;
    p0.x *= inv; p0.y *= inv; p0.z *= inv; p0.w *= inv;
    p1.x *= inv; p1.y *= inv; p1.z *= inv; p1.w *= inv;
    float* op = P + (size_t)row * NCLUST;
    *(float4*)(op + lane * 4) = p0;
    *(float4*)(op + 256 + lane * 4) = p1;
}

extern "C" void kernel_launch(void* const* d_in, const int* in_sizes, int n_in,
                              void* d_out, int out_size, void* d_ws, size_t ws_size,
                              hipStream_t stream) {
    const float* z    = (const float*)d_in[0];
    const float* cent = (const float*)d_in[1];
    float* out = (float*)d_out;

    // workspace layout
    char* ws = (char*)d_ws;
    unsigned short* zb = (unsigned short*)ws;                         // 32 MiB
    unsigned short* cb = (unsigned short*)(ws + 33554432);            // 2 MiB
    float* zsq    = (float*)(ws + 35651584);                          // 32 KiB
    float* csq    = (float*)(ws + 35684352);                          // 2 KiB
    float* colsum = (float*)(ws + 35686400);                          // 2 KiB
    float* p2     = (float*)(ws + 35688448);                          // 16 MiB
    float* p3     = (float*)(ws + 52465664);                          // 16 MiB
    const size_t WS_NEED_K4 = 69242880;

    float* Q = out;                                  // (8192, 512); scratch p0 first
    float* P = out + (size_t)M_ROWS * NCLUST;        // (8192, 512); scratch p1 first

    k_convert<<<dim3((M_ROWS + NCLUST) / 4), dim3(256), 0, stream>>>(
        z, cent, zb, cb, zsq, csq, colsum);

    if (ws_size >= WS_NEED_K4) {
        // KSPLIT=4: grid 4x64x4 = 1024 blocks -> 4 blocks/CU
        k_gemm_part<<<dim3(NCLUST / BN, M_ROWS / BM, 4), dim3(256), 0, stream>>>(
            zb, cb, Q, P, p2, p3, KDIM / 4 / BK);
        k_q_norm<4><<<dim3(M_ROWS / 32), dim3(256), 0, stream>>>(
            Q, P, p2, p3, zsq, csq, Q, colsum);
    } else {
        // KSPLIT=2 fallback: partials entirely in d_out
        k_gemm_part<<<dim3(NCLUST / BN, M_ROWS / BM, 2), dim3(256), 0, stream>>>(
            zb, cb, Q, P, p2, p3, KDIM / 2 / BK);
        k_q_norm<2><<<dim3(M_ROWS / 32), dim3(256), 0, stream>>>(
            Q, P, p2, p3, zsq, csq, Q, colsum);
    }

    k_p<<<dim3(M_ROWS / 4), dim3(256), 0, stream>>>(Q, colsum, P);
}

// Round 4
// 79.210 us; speedup vs baseline: 1.2696x; 1.0901x over previous
//
#include <hip/hip_runtime.h>
#include <stdint.h>

#define M_ROWS 8192
#define NCLUST 512
#define KDIM   2048

#define BM 128
#define BN 128
#define BK 64
#define KSPLIT 2

typedef __attribute__((ext_vector_type(8))) __bf16 bf16x8;
typedef __attribute__((ext_vector_type(4))) float  f32x4;

// round-to-nearest-even f32 -> bf16 (bit pattern)
__device__ __forceinline__ unsigned short f2bf(float f) {
    unsigned u = __float_as_uint(f);
    u += 0x7FFFu + ((u >> 16) & 1u);
    return (unsigned short)(u >> 16);
}

__device__ __forceinline__ void gload_lds16(const void* g, void* l) {
    __builtin_amdgcn_global_load_lds(
        (const __attribute__((address_space(1))) void*)g,
        (__attribute__((address_space(3))) void*)l,
        16, 0, 0);
}

// ---------------------------------------------------------------------------
// Kernel 1: f32 -> bf16 convert + per-row sum of squares. Also zeroes colsum.
// ---------------------------------------------------------------------------
__global__ __launch_bounds__(256) void k_convert(
    const float* __restrict__ z, const float* __restrict__ cent,
    unsigned short* __restrict__ zb, unsigned short* __restrict__ cb,
    float* __restrict__ zsq, float* __restrict__ csq,
    float* __restrict__ colsum)
{
    int w = threadIdx.x >> 6, lane = threadIdx.x & 63;
    int row = blockIdx.x * 4 + w;  // 0..8703

    const float* src;
    unsigned short* dst;
    float* nrm;
    int r;
    if (row < M_ROWS) { src = z + (size_t)row * KDIM; dst = zb + (size_t)row * KDIM; nrm = zsq; r = row; }
    else              { r = row - M_ROWS; src = cent + (size_t)r * KDIM; dst = cb + (size_t)r * KDIM; nrm = csq; }

    float s = 0.f;
    #pragma unroll
    for (int it = 0; it < KDIM / 256; ++it) {
        int idx = it * 256 + lane * 4;
        float4 v = *(const float4*)(src + idx);
        s += v.x * v.x + v.y * v.y + v.z * v.z + v.w * v.w;
        ushort4 o;
        o.x = f2bf(v.x); o.y = f2bf(v.y); o.z = f2bf(v.z); o.w = f2bf(v.w);
        *(ushort4*)(dst + idx) = o;
    }
    #pragma unroll
    for (int off = 32; off; off >>= 1) s += __shfl_down(s, off);
    if (lane == 0) nrm[r] = s;

    if (blockIdx.x == 0) {
        colsum[threadIdx.x] = 0.f;
        colsum[threadIdx.x + 256] = 0.f;
    }
}

// ---------------------------------------------------------------------------
// Kernel 2: split-K bf16 MFMA partial GEMM. 128x128 tile, BK=64 (m97 K-step),
// 4 waves (2x2, each 64x64 = acc[4][4], 32 MFMA per K-step).  KSPLIT=2 ->
// grid 4x64x2 = 512 blocks; LDS 64 KiB -> 2 blocks/CU co-resident.
// LDS bank swizzle (both-sides involution): row = 8 slots of 16B; physical
// slot p at row r holds logical slot p ^ (r&7).  Staged via pre-swizzled
// global source (linear LDS dest, as global_load_lds requires); ds_read
// applies the same XOR.  16-lane column reads spread over 8 slots -> 2-way.
// ---------------------------------------------------------------------------
__global__ __launch_bounds__(256) void k_gemm_part(
    const unsigned short* __restrict__ zb, const unsigned short* __restrict__ cb,
    float* __restrict__ p0, float* __restrict__ p1,
    int nkt)
{
    __shared__ unsigned short As[2][BM * BK];   // 16 KiB x2
    __shared__ unsigned short Bs[2][BN * BK];   // 16 KiB x2

    const int tid  = threadIdx.x;
    const int w    = tid >> 6, lane = tid & 63;
    const int wr   = w >> 1,  wc   = w & 1;
    const int bRow = blockIdx.y * BM;
    const int bCol = blockIdx.x * BN;
    const int kb0  = blockIdx.z * nkt * BK;

    f32x4 acc[4][4] = {};

    // staging: each wave-issue covers 8 rows x 128B (1 KiB); 16 issues per
    // matrix per K-step (4 per wave).  srow = lane>>3 (0..7), physical 16B
    // slot = lane&7; source logical slot = (lane&7) ^ (srow&7).
    const int srow = lane >> 3;
    const int scol = ((lane & 7) ^ (srow & 7)) * 8;
    const unsigned short* gA = zb + (size_t)(bRow + srow) * KDIM + kb0 + scol;
    const unsigned short* gB = cb + (size_t)(bCol + srow) * KDIM + kb0 + scol;

    auto stage = [&](int buf, int kt) {
        const int kb = kt * BK;
        #pragma unroll
        for (int j = 0; j < 4; ++j) {
            const int g = w * 4 + j;   // 8-row group 0..15
            gload_lds16(gA + (size_t)(g * 8) * KDIM + kb, &As[buf][g * 512]);
            gload_lds16(gB + (size_t)(g * 8) * KDIM + kb, &Bs[buf][g * 512]);
        }
    };

    const int arowb = wr * 64 + (lane & 15);
    const int bcolb = wc * 64 + (lane & 15);
    const int s     = lane >> 4;       // k-subslot 0..3
    const int rlow  = lane & 7;        // row&7 for all fragment rows

    auto compute = [&](int buf) {
        const unsigned short* A0 = &As[buf][0];
        const unsigned short* B0 = &Bs[buf][0];
        #pragma unroll
        for (int ks = 0; ks < 2; ++ks) {
            const int sp = (ks * 4 + s) ^ rlow;   // swizzled 16B slot 0..7
            bf16x8 af[4], bfr[4];
            #pragma unroll
            for (int i = 0; i < 4; ++i)
                af[i] = *(const bf16x8*)&A0[(arowb + i * 16) * BK + sp * 8];
            #pragma unroll
            for (int j = 0; j < 4; ++j)
                bfr[j] = *(const bf16x8*)&B0[(bcolb + j * 16) * BK + sp * 8];
            #pragma unroll
            for (int i = 0; i < 4; ++i)
                #pragma unroll
                for (int j = 0; j < 4; ++j)
                    acc[i][j] = __builtin_amdgcn_mfma_f32_16x16x32_bf16(af[i], bfr[j], acc[i][j], 0, 0, 0);
        }
    };

    stage(0, 0);
    __syncthreads();
    int buf = 0;
    for (int kt = 0; kt < nkt - 1; ++kt) {
        stage(buf ^ 1, kt + 1);
        compute(buf);
        __syncthreads();
        buf ^= 1;
    }
    compute(buf);

    float* dst = (blockIdx.z == 0) ? p0 : p1;
    // C/D frag mapping: col=lane&15, row=(lane>>4)*4+reg (m89-verified)
    const int col0 = bCol + wc * 64 + (lane & 15);
    const int row0 = bRow + wr * 64 + (lane >> 4) * 4;
    #pragma unroll
    for (int j = 0; j < 4; ++j) {
        const int col = col0 + j * 16;
        #pragma unroll
        for (int i = 0; i < 4; ++i)
            #pragma unroll
            for (int r = 0; r < 4; ++r)
                dst[(size_t)(row0 + i * 16 + r) * NCLUST + col] = acc[i][j][r];
    }
}

// ---------------------------------------------------------------------------
// Kernel 3: combine 2 partials -> Q = 1/(1+sqrt(max(zsq+csq-2*cross,0))),
// row-normalize, column-sum (LDS reduce -> atomics).  32 rows/block.
// Q aliases p0 (in-place); reads of a row complete before its Q write.
// ---------------------------------------------------------------------------
__global__ __launch_bounds__(256) void k_q_norm(
    const float* p0, const float* p1,
    const float* __restrict__ zsq, const float* __restrict__ csq,
    float* Q, float* __restrict__ colsum)
{
    __shared__ float part[4][NCLUST];
    const int tid = threadIdx.x, w = tid >> 6, lane = tid & 63;
    float ca[8] = {0, 0, 0, 0, 0, 0, 0, 0};
    const int rbase = blockIdx.x * 32;

    const float4 cs0 = *(const float4*)(csq + lane * 4);
    const float4 cs1 = *(const float4*)(csq + 256 + lane * 4);

    for (int rr = 0; rr < 8; ++rr) {
        const int row = rbase + w + rr * 4;
        const size_t off = (size_t)row * NCLUST;
        float4 x0 = *(const float4*)(p0 + off + lane * 4);
        float4 x1 = *(const float4*)(p0 + off + 256 + lane * 4);
        float4 y0 = *(const float4*)(p1 + off + lane * 4);
        float4 y1 = *(const float4*)(p1 + off + 256 + lane * 4);
        x0.x += y0.x; x0.y += y0.y; x0.z += y0.z; x0.w += y0.w;
        x1.x += y1.x; x1.y += y1.y; x1.z += y1.z; x1.w += y1.w;

        const float zr = zsq[row];
        float4 q0, q1;
        q0.x = 1.0f / (1.0f + sqrtf(fmaxf(zr + cs0.x - 2.0f * x0.x, 0.0f)));
        q0.y = 1.0f / (1.0f + sqrtf(fmaxf(zr + cs0.y - 2.0f * x0.y, 0.0f)));
        q0.z = 1.0f / (1.0f + sqrtf(fmaxf(zr + cs0.z - 2.0f * x0.z, 0.0f)));
        q0.w = 1.0f / (1.0f + sqrtf(fmaxf(zr + cs0.w - 2.0f * x0.w, 0.0f)));
        q1.x = 1.0f / (1.0f + sqrtf(fmaxf(zr + cs1.x - 2.0f * x1.x, 0.0f)));
        q1.y = 1.0f / (1.0f + sqrtf(fmaxf(zr + cs1.y - 2.0f * x1.y, 0.0f)));
        q1.z = 1.0f / (1.0f + sqrtf(fmaxf(zr + cs1.z - 2.0f * x1.z, 0.0f)));
        q1.w = 1.0f / (1.0f + sqrtf(fmaxf(zr + cs1.w - 2.0f * x1.w, 0.0f)));

        float sum = q0.x + q0.y + q0.z + q0.w + q1.x + q1.y + q1.z + q1.w;
        #pragma unroll
        for (int off2 = 32; off2; off2 >>= 1) sum += __shfl_down(sum, off2);
        sum = __shfl(sum, 0);
        const float inv = 1.0f / sum;
        q0.x *= inv; q0.y *= inv; q0.z *= inv; q0.w *= inv;
        q1.x *= inv; q1.y *= inv; q1.z *= inv; q1.w *= inv;
        *(float4*)(Q + off + lane * 4) = q0;
        *(float4*)(Q + off + 256 + lane * 4) = q1;
        ca[0] += q0.x; ca[1] += q0.y; ca[2] += q0.z; ca[3] += q0.w;
        ca[4] += q1.x; ca[5] += q1.y; ca[6] += q1.z; ca[7] += q1.w;
    }
    #pragma unroll
    for (int c = 0; c < 4; ++c) {
        part[w][lane * 4 + c]       = ca[c];
        part[w][256 + lane * 4 + c] = ca[4 + c];
    }
    __syncthreads();
    const float t0 = part[0][tid] + part[1][tid] + part[2][tid] + part[3][tid];
    const float t1 = part[0][tid + 256] + part[1][tid + 256] + part[2][tid + 256] + part[3][tid + 256];
    atomicAdd(&colsum[tid], t0);
    atomicAdd(&colsum[tid + 256], t1);
}

// ---------------------------------------------------------------------------
// Kernel 4: P = rownorm(Q^2 / colsum). One wave per row.
// ---------------------------------------------------------------------------
__global__ __launch_bounds__(256) void k_p(
    const float* __restrict__ Q, const float* __restrict__ colsum,
    float* __restrict__ P)
{
    const int w = threadIdx.x >> 6, lane = threadIdx.x & 63;
    const int row = blockIdx.x * 4 + w;
    const float* qp = Q + (size_t)row * NCLUST;
    float4 q0 = *(const float4*)(qp + lane * 4);
    float4 q1 = *(const float4*)(qp + 256 + lane * 4);
    float4 c0 = *(const float4*)(colsum + lane * 4);
    float4 c1 = *(const float4*)(colsum + 256 + lane * 4);
    float4 p0, p1;
    p0.x = q0.x * q0.x / c0.x; p0.y = q0.y * q0.y / c0.y;
    p0.z = q0.z * q0.z / c0.z; p0.w = q0.w * q0.w / c0.w;
    p1.x = q1.x * q1.x / c1.x; p1.y = q1.y * q1.y / c1.y;
    p1.z = q1.z * q1.z / c1.z; p1.w = q1.w * q1.w / c1.w;
    float s = p0.x + p0.y + p0.z + p0.w + p1.x + p1.y + p1.z + p1.w;
    #pragma unroll
    for (int off = 32; off; off >>= 1) s += __shfl_down(s, off);
    s = __shfl(s, 0);
    const float inv = 1.0f / s;
    p0.x *= inv; p0.y *= inv; p0.z *= inv; p0.w *= inv;
    p1.x *= inv; p1.y *= inv; p1.z *= inv; p1.w *= inv;
    float* op = P + (size_t)row * NCLUST;
    *(float4*)(op + lane * 4) = p0;
    *(float4*)(op + 256 + lane * 4) = p1;
}

extern "C" void kernel_launch(void* const* d_in, const int* in_sizes, int n_in,
                              void* d_out, int out_size, void* d_ws, size_t ws_size,
                              hipStream_t stream) {
    const float* z    = (const float*)d_in[0];
    const float* cent = (const float*)d_in[1];
    float* out = (float*)d_out;

    // workspace layout (needs ~35.7 MiB)
    char* ws = (char*)d_ws;
    unsigned short* zb = (unsigned short*)ws;                         // 32 MiB
    unsigned short* cb = (unsigned short*)(ws + 33554432);            // 2 MiB
    float* zsq    = (float*)(ws + 35651584);                          // 32 KiB
    float* csq    = (float*)(ws + 35684352);                          // 2 KiB
    float* colsum = (float*)(ws + 35686400);                          // 2 KiB

    float* Q = out;                                  // (8192, 512); partial p0 first
    float* P = out + (size_t)M_ROWS * NCLUST;        // (8192, 512); partial p1 first

    k_convert<<<dim3((M_ROWS + NCLUST) / 4), dim3(256), 0, stream>>>(
        z, cent, zb, cb, zsq, csq, colsum);

    // KSPLIT=2: grid 4x64x2 = 512 blocks -> 2 blocks/CU (LDS 64 KiB)
    k_gemm_part<<<dim3(NCLUST / BN, M_ROWS / BM, KSPLIT), dim3(256), 0, stream>>>(
        zb, cb, Q, P, KDIM / KSPLIT / BK);

    k_q_norm<<<dim3(M_ROWS / 32), dim3(256), 0, stream>>>(
        Q, P, zsq, csq, Q, colsum);

    k_p<<<dim3(M_ROWS / 4), dim3(256), 0, stream>>>(Q, colsum, P);
}

// Round 5
// 60.026 us; speedup vs baseline: 1.6754x; 1.3196x over previous
//
#include <hip/hip_runtime.h>
#include <stdint.h>

#define M_ROWS 8192
#define NCLUST 512
#define KDIM   2048

#define BM 128
#define BN 128
#define BKB 128      // K-step in BYTES (fp8) = 128 K-elements
#define KSPLIT 2

typedef __attribute__((ext_vector_type(4))) int   i32x4;
typedef __attribute__((ext_vector_type(8))) int   i32x8;
typedef __attribute__((ext_vector_type(4))) float f32x4;

__device__ __forceinline__ void gload_lds16(const void* g, void* l) {
    __builtin_amdgcn_global_load_lds(
        (const __attribute__((address_space(1))) void*)g,
        (__attribute__((address_space(3))) void*)l,
        16, 0, 0);
}

// ---------------------------------------------------------------------------
// Kernel 1: f32 -> fp8 e4m3 (HW v_cvt_pk_fp8_f32, RNE/sat) + per-row sum of
// squares (from the ORIGINAL f32 values, matching the reference).
// Rows 0..8191 = z, 8192..8703 = centroids. One wave per row. Zeroes colsum.
// ---------------------------------------------------------------------------
__global__ __launch_bounds__(256) void k_convert(
    const float* __restrict__ z, const float* __restrict__ cent,
    unsigned char* __restrict__ zb, unsigned char* __restrict__ cb,
    float* __restrict__ zsq, float* __restrict__ csq,
    float* __restrict__ colsum)
{
    int w = threadIdx.x >> 6, lane = threadIdx.x & 63;
    int row = blockIdx.x * 4 + w;  // 0..8703

    const float* src;
    unsigned char* dst;
    float* nrm;
    int r;
    if (row < M_ROWS) { src = z + (size_t)row * KDIM; dst = zb + (size_t)row * KDIM; nrm = zsq; r = row; }
    else              { r = row - M_ROWS; src = cent + (size_t)r * KDIM; dst = cb + (size_t)r * KDIM; nrm = csq; }

    float s = 0.f;
    #pragma unroll
    for (int it = 0; it < KDIM / 256; ++it) {
        int idx = it * 256 + lane * 4;
        float4 v = *(const float4*)(src + idx);
        s += v.x * v.x + v.y * v.y + v.z * v.z + v.w * v.w;
        int p = __builtin_amdgcn_cvt_pk_fp8_f32(v.x, v.y, 0, 0);   // bytes 0,1
        p     = __builtin_amdgcn_cvt_pk_fp8_f32(v.z, v.w, p, 1);   // bytes 2,3
        *(int*)(dst + idx) = p;
    }
    #pragma unroll
    for (int off = 32; off; off >>= 1) s += __shfl_down(s, off);
    if (lane == 0) nrm[r] = s;

    if (blockIdx.x == 0) {
        colsum[threadIdx.x] = 0.f;
        colsum[threadIdx.x + 256] = 0.f;
    }
}

// ---------------------------------------------------------------------------
// Kernel 2: split-K fp8 MFMA partial GEMM via mfma_scale_f32_16x16x128_f8f6f4
// (cbsz=blgp=0 => E4M3 A and B; scale = 0x7F => 1.0: plain fp8 matmul at 2x
// bf16 rate).  128x128 tile, K-step = 128 elements (128 bytes/row), 4 waves
// (2x2, each 64x64 = acc[4][4], 16 MFMA per K-step).  KSPLIT=2 -> grid
// 4x64x2 = 512 blocks; LDS 64 KiB -> 2 blocks/CU.  nkt = 8 (half of R4's
// barrier count; half the staged bytes).
// LDS swizzle (both-sides involution, rule #21): row = 8 slots of 16B;
// physical slot p at row r holds logical slot p ^ (r&7).  Staged via
// pre-swizzled global source (linear LDS dest); ds_read applies same XOR.
// ---------------------------------------------------------------------------
__global__ __launch_bounds__(256) void k_gemm_part(
    const unsigned char* __restrict__ zb, const unsigned char* __restrict__ cb,
    float* __restrict__ p0, float* __restrict__ p1,
    int nkt)
{
    __shared__ unsigned char As[2][BM * BKB];   // 16 KiB x2
    __shared__ unsigned char Bs[2][BN * BKB];   // 16 KiB x2

    const int tid  = threadIdx.x;
    const int w    = tid >> 6, lane = tid & 63;
    const int wr   = w >> 1,  wc   = w & 1;
    const int bRow = blockIdx.y * BM;
    const int bCol = blockIdx.x * BN;
    const size_t kb0 = (size_t)blockIdx.z * nkt * BKB;   // byte offset in K

    f32x4 acc[4][4] = {};

    // staging: each wave-issue covers 8 rows x 128B (1 KiB); 16 issues per
    // matrix per K-step (4 per wave).  srow = lane>>3 (0..7); physical 16B
    // slot = lane&7; source logical slot = (lane&7) ^ srow.
    const int srow = lane >> 3;
    const int scol = ((lane & 7) ^ srow) * 16;
    const unsigned char* gA = zb + (size_t)(bRow + srow) * KDIM + kb0 + scol;
    const unsigned char* gB = cb + (size_t)(bCol + srow) * KDIM + kb0 + scol;

    auto stage = [&](int buf, int kt) {
        const int kb = kt * BKB;
        #pragma unroll
        for (int j = 0; j < 4; ++j) {
            const int g = w * 4 + j;   // 8-row group 0..15
            gload_lds16(gA + (size_t)(g * 8) * KDIM + kb, &As[buf][g * 1024]);
            gload_lds16(gB + (size_t)(g * 8) * KDIM + kb, &Bs[buf][g * 1024]);
        }
    };

    const int arowb = wr * 64 + (lane & 15);
    const int bcolb = wc * 64 + (lane & 15);
    const int s     = lane >> 4;       // K 32-byte block 0..3
    const int r7    = lane & 7;        // row&7 for all fragment rows
    const int sc    = 0x7F7F7F7F;      // e8m0 scale 127 = 2^0 in every byte

    auto compute = [&](int buf) {
        const unsigned char* A0 = &As[buf][0];
        const unsigned char* B0 = &Bs[buf][0];
        i32x8 af[4], bf[4];
        #pragma unroll
        for (int i = 0; i < 4; ++i) {
            const int row = arowb + i * 16;
            const i32x4 lo = *(const i32x4*)&A0[row * BKB + ((2 * s) ^ r7) * 16];
            const i32x4 hi = *(const i32x4*)&A0[row * BKB + ((2 * s + 1) ^ r7) * 16];
            af[i][0] = lo[0]; af[i][1] = lo[1]; af[i][2] = lo[2]; af[i][3] = lo[3];
            af[i][4] = hi[0]; af[i][5] = hi[1]; af[i][6] = hi[2]; af[i][7] = hi[3];
        }
        #pragma unroll
        for (int j = 0; j < 4; ++j) {
            const int row = bcolb + j * 16;
            const i32x4 lo = *(const i32x4*)&B0[row * BKB + ((2 * s) ^ r7) * 16];
            const i32x4 hi = *(const i32x4*)&B0[row * BKB + ((2 * s + 1) ^ r7) * 16];
            bf[j][0] = lo[0]; bf[j][1] = lo[1]; bf[j][2] = lo[2]; bf[j][3] = lo[3];
            bf[j][4] = hi[0]; bf[j][5] = hi[1]; bf[j][6] = hi[2]; bf[j][7] = hi[3];
        }
        #pragma unroll
        for (int i = 0; i < 4; ++i)
            #pragma unroll
            for (int j = 0; j < 4; ++j)
                acc[i][j] = __builtin_amdgcn_mfma_scale_f32_16x16x128_f8f6f4(
                    af[i], bf[j], acc[i][j], 0, 0, 0, sc, 0, sc);
    };

    stage(0, 0);
    __syncthreads();
    int buf = 0;
    for (int kt = 0; kt < nkt - 1; ++kt) {
        stage(buf ^ 1, kt + 1);
        compute(buf);
        __syncthreads();
        buf ^= 1;
    }
    compute(buf);

    float* dst = (blockIdx.z == 0) ? p0 : p1;
    // C/D frag mapping: col=lane&15, row=(lane>>4)*4+reg (shape-determined,
    // dtype-independent on gfx950 -- m89/m127-verified)
    const int col0 = bCol + wc * 64 + (lane & 15);
    const int row0 = bRow + wr * 64 + (lane >> 4) * 4;
    #pragma unroll
    for (int j = 0; j < 4; ++j) {
        const int col = col0 + j * 16;
        #pragma unroll
        for (int i = 0; i < 4; ++i)
            #pragma unroll
            for (int r = 0; r < 4; ++r)
                dst[(size_t)(row0 + i * 16 + r) * NCLUST + col] = acc[i][j][r];
    }
}

// ---------------------------------------------------------------------------
// Kernel 3: combine 2 partials -> Q = 1/(1+sqrt(max(zsq+csq-2*cross,0))),
// row-normalize, column-sum (LDS reduce -> atomics).  32 rows/block.
// Q aliases p0 (in-place); reads of a row complete before its Q write.
// ---------------------------------------------------------------------------
__global__ __launch_bounds__(256) void k_q_norm(
    const float* p0, const float* p1,
    const float* __restrict__ zsq, const float* __restrict__ csq,
    float* Q, float* __restrict__ colsum)
{
    __shared__ float part[4][NCLUST];
    const int tid = threadIdx.x, w = tid >> 6, lane = tid & 63;
    float ca[8] = {0, 0, 0, 0, 0, 0, 0, 0};
    const int rbase = blockIdx.x * 32;

    const float4 cs0 = *(const float4*)(csq + lane * 4);
    const float4 cs1 = *(const float4*)(csq + 256 + lane * 4);

    for (int rr = 0; rr < 8; ++rr) {
        const int row = rbase + w + rr * 4;
        const size_t off = (size_t)row * NCLUST;
        float4 x0 = *(const float4*)(p0 + off + lane * 4);
        float4 x1 = *(const float4*)(p0 + off + 256 + lane * 4);
        float4 y0 = *(const float4*)(p1 + off + lane * 4);
        float4 y1 = *(const float4*)(p1 + off + 256 + lane * 4);
        x0.x += y0.x; x0.y += y0.y; x0.z += y0.z; x0.w += y0.w;
        x1.x += y1.x; x1.y += y1.y; x1.z += y1.z; x1.w += y1.w;

        const float zr = zsq[row];
        float4 q0, q1;
        q0.x = 1.0f / (1.0f + sqrtf(fmaxf(zr + cs0.x - 2.0f * x0.x, 0.0f)));
        q0.y = 1.0f / (1.0f + sqrtf(fmaxf(zr + cs0.y - 2.0f * x0.y, 0.0f)));
        q0.z = 1.0f / (1.0f + sqrtf(fmaxf(zr + cs0.z - 2.0f * x0.z, 0.0f)));
        q0.w = 1.0f / (1.0f + sqrtf(fmaxf(zr + cs0.w - 2.0f * x0.w, 0.0f)));
        q1.x = 1.0f / (1.0f + sqrtf(fmaxf(zr + cs1.x - 2.0f * x1.x, 0.0f)));
        q1.y = 1.0f / (1.0f + sqrtf(fmaxf(zr + cs1.y - 2.0f * x1.y, 0.0f)));
        q1.z = 1.0f / (1.0f + sqrtf(fmaxf(zr + cs1.z - 2.0f * x1.z, 0.0f)));
        q1.w = 1.0f / (1.0f + sqrtf(fmaxf(zr + cs1.w - 2.0f * x1.w, 0.0f)));

        float sum = q0.x + q0.y + q0.z + q0.w + q1.x + q1.y + q1.z + q1.w;
        #pragma unroll
        for (int off2 = 32; off2; off2 >>= 1) sum += __shfl_down(sum, off2);
        sum = __shfl(sum, 0);
        const float inv = 1.0f / sum;
        q0.x *= inv; q0.y *= inv; q0.z *= inv; q0.w *= inv;
        q1.x *= inv; q1.y *= inv; q1.z *= inv; q1.w *= inv;
        *(float4*)(Q + off + lane * 4) = q0;
        *(float4*)(Q + off + 256 + lane * 4) = q1;
        ca[0] += q0.x; ca[1] += q0.y; ca[2] += q0.z; ca[3] += q0.w;
        ca[4] += q1.x; ca[5] += q1.y; ca[6] += q1.z; ca[7] += q1.w;
    }
    #pragma unroll
    for (int c = 0; c < 4; ++c) {
        part[w][lane * 4 + c]       = ca[c];
        part[w][256 + lane * 4 + c] = ca[4 + c];
    }
    __syncthreads();
    const float t0 = part[0][tid] + part[1][tid] + part[2][tid] + part[3][tid];
    const float t1 = part[0][tid + 256] + part[1][tid + 256] + part[2][tid + 256] + part[3][tid + 256];
    atomicAdd(&colsum[tid], t0);
    atomicAdd(&colsum[tid + 256], t1);
}

// ---------------------------------------------------------------------------
// Kernel 4: P = rownorm(Q^2 / colsum). One wave per row.
// ---------------------------------------------------------------------------
__global__ __launch_bounds__(256) void k_p(
    const float* __restrict__ Q, const float* __restrict__ colsum,
    float* __restrict__ P)
{
    const int w = threadIdx.x >> 6, lane = threadIdx.x & 63;
    const int row = blockIdx.x * 4 + w;
    const float* qp = Q + (size_t)row * NCLUST;
    float4 q0 = *(const float4*)(qp + lane * 4);
    float4 q1 = *(const float4*)(qp + 256 + lane * 4);
    float4 c0 = *(const float4*)(colsum + lane * 4);
    float4 c1 = *(const float4*)(colsum + 256 + lane * 4);
    float4 p0, p1;
    p0.x = q0.x * q0.x / c0.x; p0.y = q0.y * q0.y / c0.y;
    p0.z = q0.z * q0.z / c0.z; p0.w = q0.w * q0.w / c0.w;
    p1.x = q1.x * q1.x / c1.x; p1.y = q1.y * q1.y / c1.y;
    p1.z = q1.z * q1.z / c1.z; p1.w = q1.w * q1.w / c1.w;
    float s = p0.x + p0.y + p0.z + p0.w + p1.x + p1.y + p1.z + p1.w;
    #pragma unroll
    for (int off = 32; off; off >>= 1) s += __shfl_down(s, off);
    s = __shfl(s, 0);
    const float inv = 1.0f / s;
    p0.x *= inv; p0.y *= inv; p0.z *= inv; p0.w *= inv;
    p1.x *= inv; p1.y *= inv; p1.z *= inv; p1.w *= inv;
    float* op = P + (size_t)row * NCLUST;
    *(float4*)(op + lane * 4) = p0;
    *(float4*)(op + 256 + lane * 4) = p1;
}

extern "C" void kernel_launch(void* const* d_in, const int* in_sizes, int n_in,
                              void* d_out, int out_size, void* d_ws, size_t ws_size,
                              hipStream_t stream) {
    const float* z    = (const float*)d_in[0];
    const float* cent = (const float*)d_in[1];
    float* out = (float*)d_out;

    // workspace layout (needs ~17.1 MiB)
    char* ws = (char*)d_ws;
    unsigned char* zb = (unsigned char*)ws;                 // 16 MiB fp8
    unsigned char* cb = (unsigned char*)(ws + 16777216);    // 1 MiB fp8
    float* zsq    = (float*)(ws + 17825792);                // 32 KiB
    float* csq    = (float*)(ws + 17858560);                // 2 KiB
    float* colsum = (float*)(ws + 17860608);                // 2 KiB

    float* Q = out;                                  // (8192, 512); partial p0 first
    float* P = out + (size_t)M_ROWS * NCLUST;        // (8192, 512); partial p1 first

    k_convert<<<dim3((M_ROWS + NCLUST) / 4), dim3(256), 0, stream>>>(
        z, cent, zb, cb, zsq, csq, colsum);

    // KSPLIT=2: grid 4x64x2 = 512 blocks -> 2 blocks/CU (LDS 64 KiB)
    k_gemm_part<<<dim3(NCLUST / BN, M_ROWS / BM, KSPLIT), dim3(256), 0, stream>>>(
        zb, cb, Q, P, KDIM / KSPLIT / BKB);

    k_q_norm<<<dim3(M_ROWS / 32), dim3(256), 0, stream>>>(
        Q, P, zsq, csq, Q, colsum);

    k_p<<<dim3(M_ROWS / 4), dim3(256), 0, stream>>>(Q, colsum, P);
}